// Round 1
// baseline (954.550 us; speedup 1.0000x reference)
//
#include <hip/hip_runtime.h>
#include <hip/hip_bf16.h>

#define N_NODES 100000
#define N_EDGES 1600000

// ---------------- CSR build ----------------

__global__ void hist_kernel(const int* __restrict__ row, int* __restrict__ cnt, int e) {
    int stride = gridDim.x * blockDim.x;
    for (int i = blockIdx.x * blockDim.x + threadIdx.x; i < e; i += stride)
        atomicAdd(&cnt[row[i]], 1);
}

__global__ __launch_bounds__(1024) void scan_kernel(const int* __restrict__ cnt,
                                                    int* __restrict__ rp,
                                                    int* __restrict__ cur,
                                                    int n, int total) {
    __shared__ int s[1024];
    int tid = threadIdx.x;
    int chunk = (n + 1023) >> 10;
    int lo = tid * chunk;
    int hi = lo + chunk; if (hi > n) hi = n;
    int sum = 0;
    for (int i = lo; i < hi; ++i) sum += cnt[i];
    s[tid] = sum;
    __syncthreads();
    // Hillis-Steele inclusive scan over 1024 partials
    for (int off = 1; off < 1024; off <<= 1) {
        int v = 0;
        if (tid >= off) v = s[tid - off];
        __syncthreads();
        if (tid >= off) s[tid] += v;
        __syncthreads();
    }
    int run = s[tid] - sum;   // exclusive prefix of this thread's chunk
    for (int i = lo; i < hi; ++i) { rp[i] = run; cur[i] = run; run += cnt[i]; }
    if (tid == 0) rp[n] = total;
}

__global__ void scatter_kernel(const int* __restrict__ row, const int* __restrict__ col,
                               const float* __restrict__ val, int* __restrict__ cur,
                               int* __restrict__ ecol, float* __restrict__ eval_, int e) {
    int stride = gridDim.x * blockDim.x;
    for (int i = blockIdx.x * blockDim.x + threadIdx.x; i < e; i += stride) {
        int r = row[i];
        int p = atomicAdd(&cur[r], 1);
        ecol[p] = col[i];
        eval_[p] = val[i];
    }
}

// ---------------- dense GEMM: Y[n,FOUT] = X[n,FIN] @ W[FIN,FOUT] + B ----------------
// W staged in LDS; each thread computes 4 consecutive output cols for a row.

template<int FIN, int FOUT, int RPB>
__global__ __launch_bounds__(256) void gemm_bias_kernel(const float* __restrict__ X,
                                                        const float* __restrict__ W,
                                                        const float* __restrict__ B,
                                                        float* __restrict__ Y, int n) {
    __shared__ float Ws[FIN * FOUT];
    for (int i = threadIdx.x * 4; i < FIN * FOUT; i += 256 * 4)
        *reinterpret_cast<float4*>(&Ws[i]) = *reinterpret_cast<const float4*>(&W[i]);
    __syncthreads();

    constexpr int CT = FOUT / 4;     // threads covering the column dim
    constexpr int RG = 256 / CT;     // row groups per block iteration
    const int c4 = (threadIdx.x % CT) * 4;
    const int rg = threadIdx.x / CT;
    const float4 bias = *reinterpret_cast<const float4*>(&B[c4]);

    int row_end = blockIdx.x * RPB + RPB; if (row_end > n) row_end = n;
    for (int r = blockIdx.x * RPB + rg; r < row_end; r += RG) {
        const float* xr = X + (size_t)r * FIN;
        float ax = bias.x, ay = bias.y, az = bias.z, aw = bias.w;
        #pragma unroll 8
        for (int k = 0; k < FIN; k += 4) {
            float4 xv = *reinterpret_cast<const float4*>(&xr[k]);
            float4 w0 = *reinterpret_cast<const float4*>(&Ws[(k + 0) * FOUT + c4]);
            float4 w1 = *reinterpret_cast<const float4*>(&Ws[(k + 1) * FOUT + c4]);
            float4 w2 = *reinterpret_cast<const float4*>(&Ws[(k + 2) * FOUT + c4]);
            float4 w3 = *reinterpret_cast<const float4*>(&Ws[(k + 3) * FOUT + c4]);
            ax += xv.x * w0.x + xv.y * w1.x + xv.z * w2.x + xv.w * w3.x;
            ay += xv.x * w0.y + xv.y * w1.y + xv.z * w2.y + xv.w * w3.y;
            az += xv.x * w0.z + xv.y * w1.z + xv.z * w2.z + xv.w * w3.z;
            aw += xv.x * w0.w + xv.y * w1.w + xv.z * w2.w + xv.w * w3.w;
        }
        float4 out = {ax, ay, az, aw};
        *reinterpret_cast<float4*>(&Y[(size_t)r * FOUT + c4]) = out;
    }
}

// ---------------- SpMM: Y[n,F] = sum_e val[e] * G[col[e], F], rows grouped via CSR ----------------

template<int F, int NPB, bool RELU>
__global__ __launch_bounds__(F * NPB) void spmm_kernel(const int* __restrict__ rp,
                                                       const int* __restrict__ ecol,
                                                       const float* __restrict__ eval_,
                                                       const float* __restrict__ G,
                                                       float* __restrict__ Y, int n) {
    int f = threadIdx.x % F;
    int node = blockIdx.x * NPB + threadIdx.x / F;
    if (node >= n) return;
    int e0 = rp[node], e1 = rp[node + 1];
    float acc = 0.f;
    int e = e0;
    for (; e + 4 <= e1; e += 4) {
        int c0 = ecol[e], c1 = ecol[e + 1], c2 = ecol[e + 2], c3 = ecol[e + 3];
        float v0 = eval_[e], v1 = eval_[e + 1], v2 = eval_[e + 2], v3 = eval_[e + 3];
        acc += v0 * G[c0 * F + f];
        acc += v1 * G[c1 * F + f];
        acc += v2 * G[c2 * F + f];
        acc += v3 * G[c3 * F + f];
    }
    for (; e < e1; ++e) acc += eval_[e] * G[ecol[e] * F + f];
    if (RELU) acc = fmaxf(acc, 0.f);
    Y[(size_t)node * F + f] = acc;
}

// ---------------- launch ----------------

extern "C" void kernel_launch(void* const* d_in, const int* in_sizes, int n_in,
                              void* d_out, int out_size, void* d_ws, size_t ws_size,
                              hipStream_t stream) {
    const float* x    = (const float*)d_in[0];
    const int*   arow = (const int*)d_in[1];
    const int*   acol = (const int*)d_in[2];
    const float* aval = (const float*)d_in[3];
    const float* W0   = (const float*)d_in[4];
    const float* b0   = (const float*)d_in[5];
    const float* W1   = (const float*)d_in[6];
    const float* b1   = (const float*)d_in[7];
    const float* W2   = (const float*)d_in[8];
    const float* b2   = (const float*)d_in[9];
    float* out = (float*)d_out;

    float* h_lin = (float*)d_ws;                                  // N*128
    float* h_act = h_lin + (size_t)N_NODES * 128;                 // N*128
    int*   cnt   = (int*)(h_act + (size_t)N_NODES * 128);         // N
    int*   rp    = cnt + N_NODES;                                 // N+1
    int*   cur   = rp + (N_NODES + 1);                            // N
    int*   ecol  = cur + N_NODES;                                 // E
    float* eval_ = (float*)(ecol + N_EDGES);                      // E

    // CSR build (per call; deterministic pipeline, no cached state)
    hipMemsetAsync(cnt, 0, N_NODES * sizeof(int), stream);
    hist_kernel<<<2048, 256, 0, stream>>>(arow, cnt, N_EDGES);
    scan_kernel<<<1, 1024, 0, stream>>>(cnt, rp, cur, N_NODES, N_EDGES);
    scatter_kernel<<<2048, 256, 0, stream>>>(arow, acol, aval, cur, ecol, eval_, N_EDGES);

    constexpr int RPB = 64;
    int gemm_grid = (N_NODES + RPB - 1) / RPB;

    // layer 0: linear -> spmm -> relu
    gemm_bias_kernel<128, 128, RPB><<<gemm_grid, 256, 0, stream>>>(x, W0, b0, h_lin, N_NODES);
    spmm_kernel<128, 2, true><<<(N_NODES + 1) / 2, 256, 0, stream>>>(rp, ecol, eval_, h_lin, h_act, N_NODES);

    // layer 1: linear -> spmm -> relu
    gemm_bias_kernel<128, 128, RPB><<<gemm_grid, 256, 0, stream>>>(h_act, W1, b1, h_lin, N_NODES);
    spmm_kernel<128, 2, true><<<(N_NODES + 1) / 2, 256, 0, stream>>>(rp, ecol, eval_, h_lin, h_act, N_NODES);

    // layer 2: linear -> spmm (no relu) -> d_out
    gemm_bias_kernel<128, 64, RPB><<<gemm_grid, 256, 0, stream>>>(h_act, W2, b2, h_lin, N_NODES);
    spmm_kernel<64, 4, false><<<(N_NODES + 3) / 4, 256, 0, stream>>>(rp, ecol, eval_, h_lin, out, N_NODES);
}

// Round 2
// 521.941 us; speedup vs baseline: 1.8288x; 1.8288x over previous
//
#include <hip/hip_runtime.h>
#include <hip/hip_bf16.h>

#define N_NODES 100000
#define N_EDGES 1600000

typedef __attribute__((ext_vector_type(8))) short bf16x8;
typedef __attribute__((ext_vector_type(4))) float f32x4;

__device__ inline unsigned short f2bf(float f) {
    union { float f; unsigned u; } v; v.f = f;
    unsigned r = v.u + 0x7FFF + ((v.u >> 16) & 1);   // RNE
    return (unsigned short)(r >> 16);
}
__device__ inline float bf2f(unsigned short h) {
    union { unsigned u; float f; } v; v.u = ((unsigned)h) << 16;
    return v.f;
}

// ---------------- CSR build ----------------

__global__ void hist_kernel(const int* __restrict__ row, int* __restrict__ cnt, int e) {
    int stride = gridDim.x * blockDim.x;
    for (int i = blockIdx.x * blockDim.x + threadIdx.x; i < e; i += stride)
        atomicAdd(&cnt[row[i]], 1);
}

// parallel scan, 3 kernels, all coalesced
__global__ __launch_bounds__(1024) void scan_part1(const int* __restrict__ cnt,
                                                   int* __restrict__ bsum, int n) {
    __shared__ int s[16];
    int idx = blockIdx.x * 1024 + threadIdx.x;
    int v = (idx < n) ? cnt[idx] : 0;
    for (int off = 32; off; off >>= 1) v += __shfl_down(v, off, 64);
    if ((threadIdx.x & 63) == 0) s[threadIdx.x >> 6] = v;
    __syncthreads();
    if (threadIdx.x < 16) {
        int w = s[threadIdx.x];
        for (int off = 8; off; off >>= 1) w += __shfl_down(w, off, 16);
        if (threadIdx.x == 0) bsum[blockIdx.x] = w;
    }
}

__global__ __launch_bounds__(128) void scan_part2(const int* __restrict__ bsum,
                                                  int* __restrict__ boff,
                                                  int* __restrict__ rp,
                                                  int nb, int n, int total) {
    __shared__ int s[128];
    int t = threadIdx.x;
    int v = (t < nb) ? bsum[t] : 0;
    s[t] = v;
    __syncthreads();
    for (int off = 1; off < 128; off <<= 1) {
        int u = (t >= off) ? s[t - off] : 0;
        __syncthreads();
        s[t] += u;
        __syncthreads();
    }
    if (t < nb) boff[t] = s[t] - v;   // exclusive
    if (t == 0) rp[n] = total;
}

__global__ __launch_bounds__(1024) void scan_part3(const int* __restrict__ cnt,
                                                   const int* __restrict__ boff,
                                                   int* __restrict__ rp,
                                                   int* __restrict__ cur, int n) {
    __shared__ int s[1024];
    int t = threadIdx.x;
    int idx = blockIdx.x * 1024 + t;
    int v = (idx < n) ? cnt[idx] : 0;
    s[t] = v;
    __syncthreads();
    for (int off = 1; off < 1024; off <<= 1) {
        int u = (t >= off) ? s[t - off] : 0;
        __syncthreads();
        s[t] += u;
        __syncthreads();
    }
    if (idx < n) {
        int e = boff[blockIdx.x] + s[t] - v;
        rp[idx] = e;
        cur[idx] = e;
    }
}

__global__ void scatter_kernel(const int* __restrict__ row, const int* __restrict__ col,
                               const float* __restrict__ val, int* __restrict__ cur,
                               int* __restrict__ ecol, float* __restrict__ eval_, int e) {
    int stride = gridDim.x * blockDim.x;
    for (int i = blockIdx.x * blockDim.x + threadIdx.x; i < e; i += stride) {
        int r = row[i];
        int p = atomicAdd(&cur[r], 1);
        ecol[p] = col[i];
        eval_[p] = val[i];
    }
}

// ---------------- dtype prep ----------------

__global__ void f32_to_bf16_kernel(const float* __restrict__ in, unsigned short* __restrict__ out, int n4) {
    int i = blockIdx.x * blockDim.x + threadIdx.x;
    if (i >= n4) return;
    float4 v = reinterpret_cast<const float4*>(in)[i];
    ushort4 o;
    o.x = f2bf(v.x); o.y = f2bf(v.y); o.z = f2bf(v.z); o.w = f2bf(v.w);
    reinterpret_cast<ushort4*>(out)[i] = o;
}

// Pack W [128][FOUT] f32 into MFMA B-fragment order:
// Bp[((nt*4 + kb)*64 + lane)*8 + j] = bf16(W[kb*32 + (lane>>4)*8 + j][nt*16 + (lane&15)])
template<int FOUT>
__global__ void pack_w_kernel(const float* __restrict__ W, unsigned short* __restrict__ Bp) {
    int idx = blockIdx.x * blockDim.x + threadIdx.x;
    if (idx >= FOUT * 128) return;
    int j = idx & 7, lane = (idx >> 3) & 63, kb = (idx >> 9) & 3, nt = idx >> 11;
    int k = kb * 32 + (lane >> 4) * 8 + j;
    int col = nt * 16 + (lane & 15);
    Bp[idx] = f2bf(W[k * FOUT + col]);
}

// ---------------- MFMA GEMM: Y[n][FOUT](bf16) = Xb[n][128](bf16) @ W + bias ----------------
// block = 256 threads (4 waves); wave owns 32 rows (2 m-tiles); block covers 128 rows x 64 cols.

template<int FOUT>
__global__ __launch_bounds__(256) void gemm_mfma(const unsigned short* __restrict__ Xb,
                                                 const unsigned short* __restrict__ Bp,
                                                 const float* __restrict__ bias,
                                                 unsigned short* __restrict__ Y, int n) {
    const int wave = threadIdx.x >> 6;
    const int lane = threadIdx.x & 63;
    const int l15 = lane & 15, kg = lane >> 4;
    const int nbase = blockIdx.y * 64;
    const int rowTile = blockIdx.x * 128 + wave * 32;

    int r0 = rowTile + l15;      if (r0 >= n) r0 = n - 1;
    int r1 = rowTile + 16 + l15; if (r1 >= n) r1 = n - 1;
    const bf16x8* x0 = reinterpret_cast<const bf16x8*>(Xb + (size_t)r0 * 128 + kg * 8);
    const bf16x8* x1 = reinterpret_cast<const bf16x8*>(Xb + (size_t)r1 * 128 + kg * 8);
    bf16x8 a0[4], a1[4];
    #pragma unroll
    for (int kb = 0; kb < 4; ++kb) { a0[kb] = x0[kb * 4]; a1[kb] = x1[kb * 4]; }

    f32x4 c0[4], c1[4];
    #pragma unroll
    for (int t = 0; t < 4; ++t) {
        c0[t] = (f32x4){0.f, 0.f, 0.f, 0.f};
        c1[t] = (f32x4){0.f, 0.f, 0.f, 0.f};
    }

    const bf16x8* bpv = reinterpret_cast<const bf16x8*>(Bp);
    #pragma unroll
    for (int nt = 0; nt < 4; ++nt) {
        int ntAbs = (nbase >> 4) + nt;
        const bf16x8* bp = bpv + (size_t)(ntAbs * 4) * 64 + lane;
        #pragma unroll
        for (int kb = 0; kb < 4; ++kb) {
            bf16x8 b = bp[kb * 64];
            c0[nt] = __builtin_amdgcn_mfma_f32_16x16x32_bf16(a0[kb], b, c0[nt], 0, 0, 0);
            c1[nt] = __builtin_amdgcn_mfma_f32_16x16x32_bf16(a1[kb], b, c1[nt], 0, 0, 0);
        }
    }

    // C layout: col = lane&15, row = (lane>>4)*4 + j  (guide-verified)
    #pragma unroll
    for (int nt = 0; nt < 4; ++nt) {
        int col = nbase + nt * 16 + l15;
        float bv = bias[col];
        int rb = rowTile + kg * 4;
        #pragma unroll
        for (int j = 0; j < 4; ++j) {
            int ra = rb + j;
            if (ra < n) Y[(size_t)ra * FOUT + col] = f2bf(c0[nt][j] + bv);
            int rc = rb + 16 + j;
            if (rc < n) Y[(size_t)rc * FOUT + col] = f2bf(c1[nt][j] + bv);
        }
    }
}

// ---------------- SpMM over bf16 gathers ----------------
// mid layers: F=128, one wave per node, 2 features/thread, ReLU, bf16 out

__global__ __launch_bounds__(256) void spmm_mid(const int* __restrict__ rp, const int* __restrict__ ecol,
                                                const float* __restrict__ eval_,
                                                const unsigned int* __restrict__ G,   // [n][64] u32 = 2xbf16
                                                unsigned int* __restrict__ Y, int n) {
    int node = blockIdx.x * 4 + (threadIdx.x >> 6);
    if (node >= n) return;
    int f = threadIdx.x & 63;
    int e0 = rp[node], e1 = rp[node + 1];
    float acc0 = 0.f, acc1 = 0.f;
    const unsigned* Gf = G + f;
    int e = e0;
    for (; e + 2 <= e1; e += 2) {
        int c0 = ecol[e], c1 = ecol[e + 1];
        float v0 = eval_[e], v1 = eval_[e + 1];
        unsigned g0 = Gf[(size_t)c0 * 64];
        unsigned g1 = Gf[(size_t)c1 * 64];
        acc0 += v0 * bf2f((unsigned short)g0) + v1 * bf2f((unsigned short)g1);
        acc1 += v0 * bf2f((unsigned short)(g0 >> 16)) + v1 * bf2f((unsigned short)(g1 >> 16));
    }
    if (e < e1) {
        float v = eval_[e];
        unsigned g = Gf[(size_t)ecol[e] * 64];
        acc0 += v * bf2f((unsigned short)g);
        acc1 += v * bf2f((unsigned short)(g >> 16));
    }
    acc0 = fmaxf(acc0, 0.f); acc1 = fmaxf(acc1, 0.f);
    Y[(size_t)node * 64 + f] = (unsigned)f2bf(acc0) | ((unsigned)f2bf(acc1) << 16);
}

// last layer: F=64, one wave per node, 1 feature/thread, f32 out, no relu

__global__ __launch_bounds__(256) void spmm_last(const int* __restrict__ rp, const int* __restrict__ ecol,
                                                 const float* __restrict__ eval_,
                                                 const unsigned short* __restrict__ G,  // [n][64] bf16
                                                 float* __restrict__ Y, int n) {
    int node = blockIdx.x * 4 + (threadIdx.x >> 6);
    if (node >= n) return;
    int f = threadIdx.x & 63;
    int e0 = rp[node], e1 = rp[node + 1];
    float acc = 0.f;
    const unsigned short* Gf = G + f;
    int e = e0;
    for (; e + 4 <= e1; e += 4) {
        int c0 = ecol[e], c1 = ecol[e + 1], c2 = ecol[e + 2], c3 = ecol[e + 3];
        float v0 = eval_[e], v1 = eval_[e + 1], v2 = eval_[e + 2], v3 = eval_[e + 3];
        acc += v0 * bf2f(Gf[(size_t)c0 * 64]) + v1 * bf2f(Gf[(size_t)c1 * 64]);
        acc += v2 * bf2f(Gf[(size_t)c2 * 64]) + v3 * bf2f(Gf[(size_t)c3 * 64]);
    }
    for (; e < e1; ++e) acc += eval_[e] * bf2f(Gf[(size_t)ecol[e] * 64]);
    Y[(size_t)node * 64 + f] = acc;
}

// ---------------- launch ----------------

extern "C" void kernel_launch(void* const* d_in, const int* in_sizes, int n_in,
                              void* d_out, int out_size, void* d_ws, size_t ws_size,
                              hipStream_t stream) {
    const float* x    = (const float*)d_in[0];
    const int*   arow = (const int*)d_in[1];
    const int*   acol = (const int*)d_in[2];
    const float* aval = (const float*)d_in[3];
    const float* W0   = (const float*)d_in[4];
    const float* b0   = (const float*)d_in[5];
    const float* W1   = (const float*)d_in[6];
    const float* b1   = (const float*)d_in[7];
    const float* W2   = (const float*)d_in[8];
    const float* b2   = (const float*)d_in[9];
    float* out = (float*)d_out;

    // workspace layout (bf16 buffers first, 16B-aligned)
    unsigned short* xb   = (unsigned short*)d_ws;                       // N*128
    unsigned short* hlin = xb   + (size_t)N_NODES * 128;                // N*128
    unsigned short* hact = hlin + (size_t)N_NODES * 128;                // N*128
    unsigned short* Bp0  = hact + (size_t)N_NODES * 128;                // 128*128
    unsigned short* Bp1  = Bp0 + 128 * 128;                             // 128*128
    unsigned short* Bp2  = Bp1 + 128 * 128;                             // 64*128
    int* cnt  = (int*)(Bp2 + 64 * 128);                                 // N
    int* rp   = cnt + N_NODES;                                          // N+1
    int* cur  = rp + (N_NODES + 1);                                     // N
    int* bsum = cur + N_NODES;                                          // 128
    int* boff = bsum + 128;                                             // 128
    int* ecol = boff + 128;                                             // E
    float* eval_ = (float*)(ecol + N_EDGES);                            // E

    const int NB = (N_NODES + 1023) / 1024;   // 98

    // CSR build
    hipMemsetAsync(cnt, 0, N_NODES * sizeof(int), stream);
    hist_kernel<<<1024, 256, 0, stream>>>(arow, cnt, N_EDGES);
    scan_part1<<<NB, 1024, 0, stream>>>(cnt, bsum, N_NODES);
    scan_part2<<<1, 128, 0, stream>>>(bsum, boff, rp, NB, N_NODES, N_EDGES);
    scan_part3<<<NB, 1024, 0, stream>>>(cnt, boff, rp, cur, N_NODES);
    scatter_kernel<<<2048, 256, 0, stream>>>(arow, acol, aval, cur, ecol, eval_, N_EDGES);

    // dtype prep
    int n4 = N_NODES * 128 / 4;
    f32_to_bf16_kernel<<<(n4 + 255) / 256, 256, 0, stream>>>(x, xb, n4);
    pack_w_kernel<128><<<64, 256, 0, stream>>>(W0, Bp0);
    pack_w_kernel<128><<<64, 256, 0, stream>>>(W1, Bp1);
    pack_w_kernel<64><<<32, 256, 0, stream>>>(W2, Bp2);

    dim3 gemm_grid((N_NODES + 127) / 128, 2);
    dim3 gemm_grid2((N_NODES + 127) / 128, 1);
    int spmm_grid = (N_NODES + 3) / 4;

    // layer 0
    gemm_mfma<128><<<gemm_grid, 256, 0, stream>>>(xb, Bp0, b0, hlin, N_NODES);
    spmm_mid<<<spmm_grid, 256, 0, stream>>>(rp, ecol, eval_, (const unsigned*)hlin, (unsigned*)hact, N_NODES);
    // layer 1
    gemm_mfma<128><<<gemm_grid, 256, 0, stream>>>(hact, Bp1, b1, hlin, N_NODES);
    spmm_mid<<<spmm_grid, 256, 0, stream>>>(rp, ecol, eval_, (const unsigned*)hlin, (unsigned*)hact, N_NODES);
    // layer 2
    gemm_mfma<64><<<gemm_grid2, 256, 0, stream>>>(hact, Bp2, b2, hlin, N_NODES);
    spmm_last<<<spmm_grid, 256, 0, stream>>>(rp, ecol, eval_, hlin, out, N_NODES);
}

// Round 3
// 483.414 us; speedup vs baseline: 1.9746x; 1.0797x over previous
//
#include <hip/hip_runtime.h>
#include <hip/hip_bf16.h>

#define N_NODES 100000
#define N_EDGES 1600000

typedef __attribute__((ext_vector_type(8))) short bf16x8;
typedef __attribute__((ext_vector_type(4))) float f32x4;

__device__ inline unsigned short f2bf(float f) {
    union { float f; unsigned u; } v; v.f = f;
    unsigned r = v.u + 0x7FFF + ((v.u >> 16) & 1);   // RNE
    return (unsigned short)(r >> 16);
}
__device__ inline float bf2f(unsigned short h) {
    union { unsigned u; float f; } v; v.u = ((unsigned)h) << 16;
    return v.f;
}

// ---------------- CSR build ----------------

__global__ void hist_kernel(const int* __restrict__ row, int* __restrict__ cnt, int e) {
    int stride = gridDim.x * blockDim.x;
    for (int i = blockIdx.x * blockDim.x + threadIdx.x; i < e; i += stride)
        atomicAdd(&cnt[row[i]], 1);
}

__global__ __launch_bounds__(1024) void scan_part1(const int* __restrict__ cnt,
                                                   int* __restrict__ bsum, int n) {
    __shared__ int s[16];
    int idx = blockIdx.x * 1024 + threadIdx.x;
    int v = (idx < n) ? cnt[idx] : 0;
    for (int off = 32; off; off >>= 1) v += __shfl_down(v, off, 64);
    if ((threadIdx.x & 63) == 0) s[threadIdx.x >> 6] = v;
    __syncthreads();
    if (threadIdx.x < 16) {
        int w = s[threadIdx.x];
        for (int off = 8; off; off >>= 1) w += __shfl_down(w, off, 16);
        if (threadIdx.x == 0) bsum[blockIdx.x] = w;
    }
}

__global__ __launch_bounds__(128) void scan_part2(const int* __restrict__ bsum,
                                                  int* __restrict__ boff,
                                                  int* __restrict__ rp,
                                                  int nb, int n, int total) {
    __shared__ int s[128];
    int t = threadIdx.x;
    int v = (t < nb) ? bsum[t] : 0;
    s[t] = v;
    __syncthreads();
    for (int off = 1; off < 128; off <<= 1) {
        int u = (t >= off) ? s[t - off] : 0;
        __syncthreads();
        s[t] += u;
        __syncthreads();
    }
    if (t < nb) boff[t] = s[t] - v;   // exclusive
    if (t == 0) rp[n] = total;
}

__global__ __launch_bounds__(1024) void scan_part3(const int* __restrict__ cnt,
                                                   const int* __restrict__ boff,
                                                   int* __restrict__ rp,
                                                   int* __restrict__ cur, int n) {
    __shared__ int s[1024];
    int t = threadIdx.x;
    int idx = blockIdx.x * 1024 + t;
    int v = (idx < n) ? cnt[idx] : 0;
    s[t] = v;
    __syncthreads();
    for (int off = 1; off < 1024; off <<= 1) {
        int u = (t >= off) ? s[t - off] : 0;
        __syncthreads();
        s[t] += u;
        __syncthreads();
    }
    if (idx < n) {
        int e = boff[blockIdx.x] + s[t] - v;
        rp[idx] = e;
        cur[idx] = e;
    }
}

// combined 8B record per edge: {col, val bits} -> one random line touch per edge
__global__ void scatter_kernel(const int* __restrict__ row, const int* __restrict__ col,
                               const float* __restrict__ val, int* __restrict__ cur,
                               int2* __restrict__ erec, int e) {
    int stride = gridDim.x * blockDim.x;
    for (int i = blockIdx.x * blockDim.x + threadIdx.x; i < e; i += stride) {
        int r = row[i];
        int p = atomicAdd(&cur[r], 1);
        int2 rec;
        rec.x = col[i];
        rec.y = __float_as_int(val[i]);
        erec[p] = rec;
    }
}

// ---------------- dtype prep ----------------

// Pack W [128][FOUT] f32 into MFMA B-fragment order:
// Bp[((nt*4 + kb)*64 + lane)*8 + j] = bf16(W[kb*32 + (lane>>4)*8 + j][nt*16 + (lane&15)])
template<int FOUT>
__global__ void pack_w_kernel(const float* __restrict__ W, unsigned short* __restrict__ Bp) {
    int idx = blockIdx.x * blockDim.x + threadIdx.x;
    if (idx >= FOUT * 128) return;
    int j = idx & 7, lane = (idx >> 3) & 63, kb = (idx >> 9) & 3, nt = idx >> 11;
    int k = kb * 32 + (lane >> 4) * 8 + j;
    int col = nt * 16 + (lane & 15);
    Bp[idx] = f2bf(W[k * FOUT + col]);
}

// ---------------- MFMA GEMM: Y[n][FOUT](bf16) = X[n][128] @ W + bias ----------------
// block = 256 threads (4 waves); wave owns 32 rows (2 m-tiles); block covers 128 rows x 64 cols.
// AF32: A operand read as f32 and converted in-register (layer 0 fuses the x cast).

template<int FOUT, bool AF32>
__global__ __launch_bounds__(256) void gemm_mfma(const void* __restrict__ Xv,
                                                 const unsigned short* __restrict__ Bp,
                                                 const float* __restrict__ bias,
                                                 unsigned short* __restrict__ Y, int n) {
    const int wave = threadIdx.x >> 6;
    const int lane = threadIdx.x & 63;
    const int l15 = lane & 15, kg = lane >> 4;
    const int nbase = blockIdx.y * 64;
    const int rowTile = blockIdx.x * 128 + wave * 32;

    int r0 = rowTile + l15;      if (r0 >= n) r0 = n - 1;
    int r1 = rowTile + 16 + l15; if (r1 >= n) r1 = n - 1;

    bf16x8 a0[4], a1[4];
    if constexpr (AF32) {
        const float* x0 = (const float*)Xv + (size_t)r0 * 128 + kg * 8;
        const float* x1 = (const float*)Xv + (size_t)r1 * 128 + kg * 8;
        #pragma unroll
        for (int kb = 0; kb < 4; ++kb) {
            float4 u = *reinterpret_cast<const float4*>(x0 + kb * 32);
            float4 v = *reinterpret_cast<const float4*>(x0 + kb * 32 + 4);
            a0[kb] = (bf16x8){(short)f2bf(u.x), (short)f2bf(u.y), (short)f2bf(u.z), (short)f2bf(u.w),
                              (short)f2bf(v.x), (short)f2bf(v.y), (short)f2bf(v.z), (short)f2bf(v.w)};
            float4 p = *reinterpret_cast<const float4*>(x1 + kb * 32);
            float4 q = *reinterpret_cast<const float4*>(x1 + kb * 32 + 4);
            a1[kb] = (bf16x8){(short)f2bf(p.x), (short)f2bf(p.y), (short)f2bf(p.z), (short)f2bf(p.w),
                              (short)f2bf(q.x), (short)f2bf(q.y), (short)f2bf(q.z), (short)f2bf(q.w)};
        }
    } else {
        const bf16x8* x0 = reinterpret_cast<const bf16x8*>((const unsigned short*)Xv + (size_t)r0 * 128 + kg * 8);
        const bf16x8* x1 = reinterpret_cast<const bf16x8*>((const unsigned short*)Xv + (size_t)r1 * 128 + kg * 8);
        #pragma unroll
        for (int kb = 0; kb < 4; ++kb) { a0[kb] = x0[kb * 4]; a1[kb] = x1[kb * 4]; }
    }

    f32x4 c0[4], c1[4];
    #pragma unroll
    for (int t = 0; t < 4; ++t) {
        c0[t] = (f32x4){0.f, 0.f, 0.f, 0.f};
        c1[t] = (f32x4){0.f, 0.f, 0.f, 0.f};
    }

    const bf16x8* bpv = reinterpret_cast<const bf16x8*>(Bp);
    #pragma unroll
    for (int nt = 0; nt < 4; ++nt) {
        int ntAbs = (nbase >> 4) + nt;
        const bf16x8* bp = bpv + (size_t)(ntAbs * 4) * 64 + lane;
        #pragma unroll
        for (int kb = 0; kb < 4; ++kb) {
            bf16x8 b = bp[kb * 64];
            c0[nt] = __builtin_amdgcn_mfma_f32_16x16x32_bf16(a0[kb], b, c0[nt], 0, 0, 0);
            c1[nt] = __builtin_amdgcn_mfma_f32_16x16x32_bf16(a1[kb], b, c1[nt], 0, 0, 0);
        }
    }

    // C layout: col = lane&15, row = (lane>>4)*4 + j
    #pragma unroll
    for (int nt = 0; nt < 4; ++nt) {
        int col = nbase + nt * 16 + l15;
        float bv = bias[col];
        int rb = rowTile + kg * 4;
        #pragma unroll
        for (int j = 0; j < 4; ++j) {
            int ra = rb + j;
            if (ra < n) Y[(size_t)ra * FOUT + col] = f2bf(c0[nt][j] + bv);
            int rc = rb + 16 + j;
            if (rc < n) Y[(size_t)rc * FOUT + col] = f2bf(c1[nt][j] + bv);
        }
    }
}

// ---------------- SpMM over bf16 gathers ----------------
// mid layers: F=128, one wave per node, 2 features/thread, ReLU, bf16 out

__global__ __launch_bounds__(256) void spmm_mid(const int* __restrict__ rp,
                                                const int2* __restrict__ erec,
                                                const unsigned int* __restrict__ G,   // [n][64] u32 = 2xbf16
                                                unsigned int* __restrict__ Y, int n) {
    int node = blockIdx.x * 4 + (threadIdx.x >> 6);
    if (node >= n) return;
    int f = threadIdx.x & 63;
    int e0 = rp[node], e1 = rp[node + 1];
    float acc0 = 0.f, acc1 = 0.f;
    const unsigned* Gf = G + f;
    int e = e0;
    for (; e + 4 <= e1; e += 4) {
        int2 q0 = erec[e], q1 = erec[e + 1], q2 = erec[e + 2], q3 = erec[e + 3];
        unsigned g0 = Gf[(size_t)q0.x * 64];
        unsigned g1 = Gf[(size_t)q1.x * 64];
        unsigned g2 = Gf[(size_t)q2.x * 64];
        unsigned g3 = Gf[(size_t)q3.x * 64];
        float v0 = __int_as_float(q0.y), v1 = __int_as_float(q1.y);
        float v2 = __int_as_float(q2.y), v3 = __int_as_float(q3.y);
        acc0 += v0 * bf2f((unsigned short)g0) + v1 * bf2f((unsigned short)g1)
              + v2 * bf2f((unsigned short)g2) + v3 * bf2f((unsigned short)g3);
        acc1 += v0 * bf2f((unsigned short)(g0 >> 16)) + v1 * bf2f((unsigned short)(g1 >> 16))
              + v2 * bf2f((unsigned short)(g2 >> 16)) + v3 * bf2f((unsigned short)(g3 >> 16));
    }
    for (; e < e1; ++e) {
        int2 q = erec[e];
        float v = __int_as_float(q.y);
        unsigned g = Gf[(size_t)q.x * 64];
        acc0 += v * bf2f((unsigned short)g);
        acc1 += v * bf2f((unsigned short)(g >> 16));
    }
    acc0 = fmaxf(acc0, 0.f); acc1 = fmaxf(acc1, 0.f);
    Y[(size_t)node * 64 + f] = (unsigned)f2bf(acc0) | ((unsigned)f2bf(acc1) << 16);
}

// last layer: F=64, one wave per node, 1 feature/thread, f32 out, no relu

__global__ __launch_bounds__(256) void spmm_last(const int* __restrict__ rp,
                                                 const int2* __restrict__ erec,
                                                 const unsigned short* __restrict__ G,  // [n][64] bf16
                                                 float* __restrict__ Y, int n) {
    int node = blockIdx.x * 4 + (threadIdx.x >> 6);
    if (node >= n) return;
    int f = threadIdx.x & 63;
    int e0 = rp[node], e1 = rp[node + 1];
    float acc = 0.f;
    const unsigned short* Gf = G + f;
    int e = e0;
    for (; e + 4 <= e1; e += 4) {
        int2 q0 = erec[e], q1 = erec[e + 1], q2 = erec[e + 2], q3 = erec[e + 3];
        acc += __int_as_float(q0.y) * bf2f(Gf[(size_t)q0.x * 64])
             + __int_as_float(q1.y) * bf2f(Gf[(size_t)q1.x * 64])
             + __int_as_float(q2.y) * bf2f(Gf[(size_t)q2.x * 64])
             + __int_as_float(q3.y) * bf2f(Gf[(size_t)q3.x * 64]);
    }
    for (; e < e1; ++e) {
        int2 q = erec[e];
        acc += __int_as_float(q.y) * bf2f(Gf[(size_t)q.x * 64]);
    }
    Y[(size_t)node * 64 + f] = acc;
}

// ---------------- launch ----------------

extern "C" void kernel_launch(void* const* d_in, const int* in_sizes, int n_in,
                              void* d_out, int out_size, void* d_ws, size_t ws_size,
                              hipStream_t stream) {
    const float* x    = (const float*)d_in[0];
    const int*   arow = (const int*)d_in[1];
    const int*   acol = (const int*)d_in[2];
    const float* aval = (const float*)d_in[3];
    const float* W0   = (const float*)d_in[4];
    const float* b0   = (const float*)d_in[5];
    const float* W1   = (const float*)d_in[6];
    const float* b1   = (const float*)d_in[7];
    const float* W2   = (const float*)d_in[8];
    const float* b2   = (const float*)d_in[9];
    float* out = (float*)d_out;

    // workspace layout (16B-aligned pieces)
    unsigned short* hlin = (unsigned short*)d_ws;                       // N*128
    unsigned short* hact = hlin + (size_t)N_NODES * 128;                // N*128
    unsigned short* Bp0  = hact + (size_t)N_NODES * 128;                // 128*128
    unsigned short* Bp1  = Bp0 + 128 * 128;                             // 128*128
    unsigned short* Bp2  = Bp1 + 128 * 128;                             // 64*128
    int* cnt  = (int*)(Bp2 + 64 * 128);                                 // N
    int* rp   = cnt + N_NODES;                                          // N+1
    int* cur  = rp + (N_NODES + 1);                                     // N
    int* bsum = cur + N_NODES;                                          // 128
    int* boff = bsum + 128;                                             // 128 (+1 pad for int2 align)
    int2* erec = (int2*)(boff + 129);                                   // E * 8B
    // total ≈ 51.2MB + 80KB + 1.2MB + 12.8MB — well under prior footprint

    const int NB = (N_NODES + 1023) / 1024;   // 98

    // CSR build
    hipMemsetAsync(cnt, 0, N_NODES * sizeof(int), stream);
    hist_kernel<<<1024, 256, 0, stream>>>(arow, cnt, N_EDGES);
    scan_part1<<<NB, 1024, 0, stream>>>(cnt, bsum, N_NODES);
    scan_part2<<<1, 128, 0, stream>>>(bsum, boff, rp, NB, N_NODES, N_EDGES);
    scan_part3<<<NB, 1024, 0, stream>>>(cnt, boff, rp, cur, N_NODES);
    scatter_kernel<<<2048, 256, 0, stream>>>(arow, acol, aval, cur, erec, N_EDGES);

    // weight packs
    pack_w_kernel<128><<<64, 256, 0, stream>>>(W0, Bp0);
    pack_w_kernel<128><<<64, 256, 0, stream>>>(W1, Bp1);
    pack_w_kernel<64><<<32, 256, 0, stream>>>(W2, Bp2);

    dim3 gemm_grid((N_NODES + 127) / 128, 2);
    dim3 gemm_grid2((N_NODES + 127) / 128, 1);
    int spmm_grid = (N_NODES + 3) / 4;

    // layer 0 (A read as f32 — x cast fused into GEMM)
    gemm_mfma<128, true><<<gemm_grid, 256, 0, stream>>>(x, Bp0, b0, hlin, N_NODES);
    spmm_mid<<<spmm_grid, 256, 0, stream>>>(rp, erec, (const unsigned*)hlin, (unsigned*)hact, N_NODES);
    // layer 1
    gemm_mfma<128, false><<<gemm_grid, 256, 0, stream>>>(hact, Bp1, b1, hlin, N_NODES);
    spmm_mid<<<spmm_grid, 256, 0, stream>>>(rp, erec, (const unsigned*)hlin, (unsigned*)hact, N_NODES);
    // layer 2
    gemm_mfma<64, false><<<gemm_grid2, 256, 0, stream>>>(hact, Bp2, b2, hlin, N_NODES);
    spmm_last<<<spmm_grid, 256, 0, stream>>>(rp, erec, hlin, out, N_NODES);
}

// Round 4
// 350.712 us; speedup vs baseline: 2.7217x; 1.3784x over previous
//
#include <hip/hip_runtime.h>
#include <hip/hip_bf16.h>

#define N_NODES 100000
#define N_EDGES 1600000

// partition geometry
#define BIN_SHIFT 9
#define NBIN 196                 // ceil(100000 / 512)
#define NBLK 256                 // partition blocks
#define CHUNK 6250               // N_EDGES / NBLK (exact)
#define SCAN_N (NBIN * NBLK)     // 50176

typedef __attribute__((ext_vector_type(8))) short bf16x8;
typedef __attribute__((ext_vector_type(4))) float f32x4;

__device__ inline unsigned short f2bf(float f) {
    union { float f; unsigned u; } v; v.f = f;
    unsigned r = v.u + 0x7FFF + ((v.u >> 16) & 1);   // RNE
    return (unsigned short)(r >> 16);
}
__device__ inline float bf2f(unsigned short h) {
    union { unsigned u; float f; } v; v.u = ((unsigned)h) << 16;
    return v.f;
}

// ---------------- binned partition (CSR build without random global writes) ----------------

// P1: per-block bin histogram -> cnt[bin][blk]
__global__ __launch_bounds__(256) void p1_bincnt(const int* __restrict__ row,
                                                 int* __restrict__ cnt) {
    __shared__ int h[NBIN];
    for (int i = threadIdx.x; i < NBIN; i += 256) h[i] = 0;
    __syncthreads();
    int base = blockIdx.x * CHUNK;
    int end = base + CHUNK; if (end > N_EDGES) end = N_EDGES;
    for (int i = base + threadIdx.x; i < end; i += 256)
        atomicAdd(&h[row[i] >> BIN_SHIFT], 1);
    __syncthreads();
    for (int b = threadIdx.x; b < NBIN; b += 256)
        cnt[b * NBLK + blockIdx.x] = h[b];
}

// P2: exclusive scan over the [bin][blk] matrix (bin-major order); also rp[N]=E
__global__ __launch_bounds__(1024) void p2_scan(const int* __restrict__ cnt,
                                                int* __restrict__ base,
                                                int* __restrict__ rp) {
    __shared__ int s[1024];
    int t = threadIdx.x;
    const int per = SCAN_N / 1024;   // 49, exact
    int lo = t * per, hi = lo + per;
    int sum = 0;
    for (int i = lo; i < hi; ++i) sum += cnt[i];
    s[t] = sum;
    __syncthreads();
    for (int off = 1; off < 1024; off <<= 1) {
        int v = (t >= off) ? s[t - off] : 0;
        __syncthreads();
        s[t] += v;
        __syncthreads();
    }
    int run = s[t] - sum;   // exclusive prefix
    for (int i = lo; i < hi; ++i) { int c = cnt[i]; base[i] = run; run += c; }
    if (t == 0) rp[N_NODES] = N_EDGES;
}

// P3: place each edge into its (block,bin) private run. meta = col | rowlocal<<17 (26 bits)
__global__ __launch_bounds__(256) void p3_partition(const int* __restrict__ row,
                                                    const int* __restrict__ col,
                                                    const float* __restrict__ val,
                                                    const int* __restrict__ base,
                                                    int2* __restrict__ bout) {
    __shared__ int cur[NBIN];
    for (int i = threadIdx.x; i < NBIN; i += 256)
        cur[i] = base[i * NBLK + blockIdx.x];
    __syncthreads();
    int lo = blockIdx.x * CHUNK;
    int end = lo + CHUNK; if (end > N_EDGES) end = N_EDGES;
    for (int i = lo + threadIdx.x; i < end; i += 256) {
        int r = row[i];
        int b = r >> BIN_SHIFT;
        int p = atomicAdd(&cur[b], 1);
        int2 rec;
        rec.x = col[i] | ((r & 511) << 17);
        rec.y = __float_as_int(val[i]);
        bout[p] = rec;
    }
}

// P4: one block per bin: LDS row-hist + scan -> rp slice, then exact placement.
__global__ __launch_bounds__(256) void p4_binscatter(const int* __restrict__ base,
                                                     const int2* __restrict__ bin_in,
                                                     int* __restrict__ rp,
                                                     int2* __restrict__ erec) {
    __shared__ int cnt[512];
    __shared__ int part[256];
    const int b = blockIdx.x;
    const int t = threadIdx.x;
    const int lo = base[b * NBLK];
    const int hi = (b + 1 < NBIN) ? base[(b + 1) * NBLK] : N_EDGES;

    cnt[t] = 0; cnt[t + 256] = 0;
    __syncthreads();
    for (int e = lo + t; e < hi; e += 256)
        atomicAdd(&cnt[(unsigned)bin_in[e].x >> 17], 1);
    __syncthreads();

    // exclusive scan of 512 counts with 256 threads (2 per thread)
    int s0 = cnt[2 * t], s1 = cnt[2 * t + 1];
    int tsum = s0 + s1;
    part[t] = tsum;
    __syncthreads();
    for (int off = 1; off < 256; off <<= 1) {
        int v = (t >= off) ? part[t - off] : 0;
        __syncthreads();
        part[t] += v;
        __syncthreads();
    }
    int run = part[t] - tsum;
    cnt[2 * t] = run;
    cnt[2 * t + 1] = run + s0;

    const int rowbase = b << BIN_SHIFT;
    int r0 = rowbase + 2 * t, r1 = rowbase + 2 * t + 1;
    if (r0 < N_NODES) rp[r0] = lo + run;
    if (r1 < N_NODES) rp[r1] = lo + run + s0;
    __syncthreads();

    for (int e = lo + t; e < hi; e += 256) {
        int2 q = bin_in[e];
        int rl = (unsigned)q.x >> 17;
        int p = lo + atomicAdd(&cnt[rl], 1);
        int2 rec;
        rec.x = q.x & 0x1FFFF;
        rec.y = q.y;
        erec[p] = rec;
    }
}

// ---------------- dtype prep ----------------

// Pack W [128][FOUT] f32 into MFMA B-fragment order:
// Bp[((nt*4 + kb)*64 + lane)*8 + j] = bf16(W[kb*32 + (lane>>4)*8 + j][nt*16 + (lane&15)])
template<int FOUT>
__global__ void pack_w_kernel(const float* __restrict__ W, unsigned short* __restrict__ Bp) {
    int idx = blockIdx.x * blockDim.x + threadIdx.x;
    if (idx >= FOUT * 128) return;
    int j = idx & 7, lane = (idx >> 3) & 63, kb = (idx >> 9) & 3, nt = idx >> 11;
    int k = kb * 32 + (lane >> 4) * 8 + j;
    int col = nt * 16 + (lane & 15);
    Bp[idx] = f2bf(W[k * FOUT + col]);
}

// ---------------- MFMA GEMM: Y[n][FOUT](bf16) = X[n][128] @ W + bias ----------------

template<int FOUT, bool AF32>
__global__ __launch_bounds__(256) void gemm_mfma(const void* __restrict__ Xv,
                                                 const unsigned short* __restrict__ Bp,
                                                 const float* __restrict__ bias,
                                                 unsigned short* __restrict__ Y, int n) {
    const int wave = threadIdx.x >> 6;
    const int lane = threadIdx.x & 63;
    const int l15 = lane & 15, kg = lane >> 4;
    const int nbase = blockIdx.y * 64;
    const int rowTile = blockIdx.x * 128 + wave * 32;

    int r0 = rowTile + l15;      if (r0 >= n) r0 = n - 1;
    int r1 = rowTile + 16 + l15; if (r1 >= n) r1 = n - 1;

    bf16x8 a0[4], a1[4];
    if constexpr (AF32) {
        const float* x0 = (const float*)Xv + (size_t)r0 * 128 + kg * 8;
        const float* x1 = (const float*)Xv + (size_t)r1 * 128 + kg * 8;
        #pragma unroll
        for (int kb = 0; kb < 4; ++kb) {
            float4 u = *reinterpret_cast<const float4*>(x0 + kb * 32);
            float4 v = *reinterpret_cast<const float4*>(x0 + kb * 32 + 4);
            a0[kb] = (bf16x8){(short)f2bf(u.x), (short)f2bf(u.y), (short)f2bf(u.z), (short)f2bf(u.w),
                              (short)f2bf(v.x), (short)f2bf(v.y), (short)f2bf(v.z), (short)f2bf(v.w)};
            float4 p = *reinterpret_cast<const float4*>(x1 + kb * 32);
            float4 q = *reinterpret_cast<const float4*>(x1 + kb * 32 + 4);
            a1[kb] = (bf16x8){(short)f2bf(p.x), (short)f2bf(p.y), (short)f2bf(p.z), (short)f2bf(p.w),
                              (short)f2bf(q.x), (short)f2bf(q.y), (short)f2bf(q.z), (short)f2bf(q.w)};
        }
    } else {
        const bf16x8* x0 = reinterpret_cast<const bf16x8*>((const unsigned short*)Xv + (size_t)r0 * 128 + kg * 8);
        const bf16x8* x1 = reinterpret_cast<const bf16x8*>((const unsigned short*)Xv + (size_t)r1 * 128 + kg * 8);
        #pragma unroll
        for (int kb = 0; kb < 4; ++kb) { a0[kb] = x0[kb * 4]; a1[kb] = x1[kb * 4]; }
    }

    f32x4 c0[4], c1[4];
    #pragma unroll
    for (int t = 0; t < 4; ++t) {
        c0[t] = (f32x4){0.f, 0.f, 0.f, 0.f};
        c1[t] = (f32x4){0.f, 0.f, 0.f, 0.f};
    }

    const bf16x8* bpv = reinterpret_cast<const bf16x8*>(Bp);
    #pragma unroll
    for (int nt = 0; nt < 4; ++nt) {
        int ntAbs = (nbase >> 4) + nt;
        const bf16x8* bp = bpv + (size_t)(ntAbs * 4) * 64 + lane;
        #pragma unroll
        for (int kb = 0; kb < 4; ++kb) {
            bf16x8 b = bp[kb * 64];
            c0[nt] = __builtin_amdgcn_mfma_f32_16x16x32_bf16(a0[kb], b, c0[nt], 0, 0, 0);
            c1[nt] = __builtin_amdgcn_mfma_f32_16x16x32_bf16(a1[kb], b, c1[nt], 0, 0, 0);
        }
    }

    // C layout: col = lane&15, row = (lane>>4)*4 + j
    #pragma unroll
    for (int nt = 0; nt < 4; ++nt) {
        int col = nbase + nt * 16 + l15;
        float bv = bias[col];
        int rb = rowTile + kg * 4;
        #pragma unroll
        for (int j = 0; j < 4; ++j) {
            int ra = rb + j;
            if (ra < n) Y[(size_t)ra * FOUT + col] = f2bf(c0[nt][j] + bv);
            int rc = rb + 16 + j;
            if (rc < n) Y[(size_t)rc * FOUT + col] = f2bf(c1[nt][j] + bv);
        }
    }
}

// ---------------- SpMM over bf16 gathers ----------------

__global__ __launch_bounds__(256) void spmm_mid(const int* __restrict__ rp,
                                                const int2* __restrict__ erec,
                                                const unsigned int* __restrict__ G,   // [n][64] u32 = 2xbf16
                                                unsigned int* __restrict__ Y, int n) {
    int node = blockIdx.x * 4 + (threadIdx.x >> 6);
    if (node >= n) return;
    int f = threadIdx.x & 63;
    int e0 = rp[node], e1 = rp[node + 1];
    float acc0 = 0.f, acc1 = 0.f;
    const unsigned* Gf = G + f;
    int e = e0;
    for (; e + 4 <= e1; e += 4) {
        int2 q0 = erec[e], q1 = erec[e + 1], q2 = erec[e + 2], q3 = erec[e + 3];
        unsigned g0 = Gf[(size_t)q0.x * 64];
        unsigned g1 = Gf[(size_t)q1.x * 64];
        unsigned g2 = Gf[(size_t)q2.x * 64];
        unsigned g3 = Gf[(size_t)q3.x * 64];
        float v0 = __int_as_float(q0.y), v1 = __int_as_float(q1.y);
        float v2 = __int_as_float(q2.y), v3 = __int_as_float(q3.y);
        acc0 += v0 * bf2f((unsigned short)g0) + v1 * bf2f((unsigned short)g1)
              + v2 * bf2f((unsigned short)g2) + v3 * bf2f((unsigned short)g3);
        acc1 += v0 * bf2f((unsigned short)(g0 >> 16)) + v1 * bf2f((unsigned short)(g1 >> 16))
              + v2 * bf2f((unsigned short)(g2 >> 16)) + v3 * bf2f((unsigned short)(g3 >> 16));
    }
    for (; e < e1; ++e) {
        int2 q = erec[e];
        float v = __int_as_float(q.y);
        unsigned g = Gf[(size_t)q.x * 64];
        acc0 += v * bf2f((unsigned short)g);
        acc1 += v * bf2f((unsigned short)(g >> 16));
    }
    acc0 = fmaxf(acc0, 0.f); acc1 = fmaxf(acc1, 0.f);
    Y[(size_t)node * 64 + f] = (unsigned)f2bf(acc0) | ((unsigned)f2bf(acc1) << 16);
}

__global__ __launch_bounds__(256) void spmm_last(const int* __restrict__ rp,
                                                 const int2* __restrict__ erec,
                                                 const unsigned short* __restrict__ G,  // [n][64] bf16
                                                 float* __restrict__ Y, int n) {
    int node = blockIdx.x * 4 + (threadIdx.x >> 6);
    if (node >= n) return;
    int f = threadIdx.x & 63;
    int e0 = rp[node], e1 = rp[node + 1];
    float acc = 0.f;
    const unsigned short* Gf = G + f;
    int e = e0;
    for (; e + 4 <= e1; e += 4) {
        int2 q0 = erec[e], q1 = erec[e + 1], q2 = erec[e + 2], q3 = erec[e + 3];
        acc += __int_as_float(q0.y) * bf2f(Gf[(size_t)q0.x * 64])
             + __int_as_float(q1.y) * bf2f(Gf[(size_t)q1.x * 64])
             + __int_as_float(q2.y) * bf2f(Gf[(size_t)q2.x * 64])
             + __int_as_float(q3.y) * bf2f(Gf[(size_t)q3.x * 64]);
    }
    for (; e < e1; ++e) {
        int2 q = erec[e];
        acc += __int_as_float(q.y) * bf2f(Gf[(size_t)q.x * 64]);
    }
    Y[(size_t)node * 64 + f] = acc;
}

// ---------------- launch ----------------

extern "C" void kernel_launch(void* const* d_in, const int* in_sizes, int n_in,
                              void* d_out, int out_size, void* d_ws, size_t ws_size,
                              hipStream_t stream) {
    const float* x    = (const float*)d_in[0];
    const int*   arow = (const int*)d_in[1];
    const int*   acol = (const int*)d_in[2];
    const float* aval = (const float*)d_in[3];
    const float* W0   = (const float*)d_in[4];
    const float* b0   = (const float*)d_in[5];
    const float* W1   = (const float*)d_in[6];
    const float* b1   = (const float*)d_in[7];
    const float* W2   = (const float*)d_in[8];
    const float* b2   = (const float*)d_in[9];
    float* out = (float*)d_out;

    // workspace layout (all pieces keep 8B alignment)
    unsigned short* hlin = (unsigned short*)d_ws;                       // N*128 u16
    unsigned short* hact = hlin + (size_t)N_NODES * 128;                // N*128 u16
    unsigned short* Bp0  = hact + (size_t)N_NODES * 128;                // 16384 u16
    unsigned short* Bp1  = Bp0 + 128 * 128;                             // 16384 u16
    unsigned short* Bp2  = Bp1 + 128 * 128;                             // 8192 u16
    int* cnt   = (int*)(Bp2 + 64 * 128);                                // NBIN*NBLK
    int* base  = cnt + SCAN_N;                                          // NBIN*NBLK
    int* rp    = base + SCAN_N;                                         // N+2 (pad for align)
    int2* bin_in = (int2*)(rp + N_NODES + 2);                           // E
    int2* erec   = bin_in + N_EDGES;                                    // E

    // partition / CSR build
    p1_bincnt<<<NBLK, 256, 0, stream>>>(arow, cnt);
    p2_scan<<<1, 1024, 0, stream>>>(cnt, base, rp);
    p3_partition<<<NBLK, 256, 0, stream>>>(arow, acol, aval, base, bin_in);
    p4_binscatter<<<NBIN, 256, 0, stream>>>(base, bin_in, rp, erec);

    // weight packs
    pack_w_kernel<128><<<64, 256, 0, stream>>>(W0, Bp0);
    pack_w_kernel<128><<<64, 256, 0, stream>>>(W1, Bp1);
    pack_w_kernel<64><<<32, 256, 0, stream>>>(W2, Bp2);

    dim3 gemm_grid((N_NODES + 127) / 128, 2);
    dim3 gemm_grid2((N_NODES + 127) / 128, 1);
    int spmm_grid = (N_NODES + 3) / 4;

    // layer 0 (A read as f32 — x cast fused into GEMM)
    gemm_mfma<128, true><<<gemm_grid, 256, 0, stream>>>(x, Bp0, b0, hlin, N_NODES);
    spmm_mid<<<spmm_grid, 256, 0, stream>>>(rp, erec, (const unsigned*)hlin, (unsigned*)hact, N_NODES);
    // layer 1
    gemm_mfma<128, false><<<gemm_grid, 256, 0, stream>>>(hact, Bp1, b1, hlin, N_NODES);
    spmm_mid<<<spmm_grid, 256, 0, stream>>>(rp, erec, (const unsigned*)hlin, (unsigned*)hact, N_NODES);
    // layer 2
    gemm_mfma<64, false><<<gemm_grid2, 256, 0, stream>>>(hact, Bp2, b2, hlin, N_NODES);
    spmm_last<<<spmm_grid, 256, 0, stream>>>(rp, erec, hlin, out, N_NODES);
}